// Round 2
// baseline (760.186 us; speedup 1.0000x reference)
//
#include <hip/hip_runtime.h>

#define CDIM 128
#define BT 128          // threads per block for GEMM kernels
#define TILE_R 32       // rows (nodes/edges) per block

// d_ws float layout:
// [0,16384)          WkT   (transposed: Wt[c*128+j] = W[j*128+c])
// [16384,32768)      WvT
// [32768,49152)      WrT
// [49152,65536)      WoT
// [65536, +3*N*C)    K ; then V ; then R

__device__ __forceinline__ void fma4(float4& acc, float s, const float4& wv) {
  acc.x += s * wv.x;
  acc.y += s * wv.y;
  acc.z += s * wv.z;
  acc.w += s * wv.w;
}

__global__ __launch_bounds__(256) void transpose_w(
    const float* __restrict__ Wk, const float* __restrict__ Wv,
    const float* __restrict__ Wr, const float* __restrict__ Wo,
    float* __restrict__ wt) {
  __shared__ float tile[32][33];
  const int m = blockIdx.x >> 4;
  const int tl = blockIdx.x & 15;
  const int tr = (tl >> 2) * 32, tc = (tl & 3) * 32;
  const float* W = (m == 0) ? Wk : (m == 1) ? Wv : (m == 2) ? Wr : Wo;
  float* Wt = wt + m * 16384;
  const int c = threadIdx.x & 31, r8 = threadIdx.x >> 5;
  for (int rr = r8; rr < 32; rr += 8)
    tile[rr][c] = W[(tr + rr) * CDIM + tc + c];
  __syncthreads();
  for (int rr = r8; rr < 32; rr += 8)
    Wt[(tc + rr) * CDIM + tr + c] = tile[c][rr];
}

// copy one 64-row half of a transposed 128x128 weight into LDS (32 KB)
__device__ __forceinline__ void copy_w_half(float* Ws, const float* Wt,
                                            int half, int t) {
  const float4* src = (const float4*)(Wt + half * 64 * CDIM);
  float4* dst = (float4*)Ws;
#pragma unroll
  for (int mm = 0; mm < 16; ++mm)
    dst[mm * BT + t] = src[mm * BT + t];
}

// accumulate 64 c-steps: acc(4 rows x 8 cols) += Ps[r, c] * Ws[c][j]
__device__ __forceinline__ void gemm_half(const float* Ws, const float* Ps,
                                          int cbase, int r0, int j0,
                                          float4 aA[4], float4 aB[4]) {
#pragma unroll 8
  for (int cc = 0; cc < 64; ++cc) {
    const float* wrow = Ws + cc * CDIM;
    float4 wA = *(const float4*)(wrow + j0);
    float4 wB = *(const float4*)(wrow + 64 + j0);
    const int c = cbase + cc;
    float x0 = Ps[(r0 + 0) * CDIM + c];
    float x1 = Ps[(r0 + 1) * CDIM + c];
    float x2 = Ps[(r0 + 2) * CDIM + c];
    float x3 = Ps[(r0 + 3) * CDIM + c];
    fma4(aA[0], x0, wA); fma4(aB[0], x0, wB);
    fma4(aA[1], x1, wA); fma4(aB[1], x1, wB);
    fma4(aA[2], x2, wA); fma4(aB[2], x2, wB);
    fma4(aA[3], x3, wA); fma4(aB[3], x3, wB);
  }
}

// ---------------- Kernel A: node stage  K/V/R = mix(x,px) @ W^T --------------
__global__ __launch_bounds__(BT) void node_stage(
    const float* __restrict__ x, const float* __restrict__ px,
    const float* __restrict__ tmk, const float* __restrict__ tmv,
    const float* __restrict__ tmr, const float* __restrict__ wt,
    float* __restrict__ kvr, int N) {
  __shared__ float Ws[64 * CDIM];      // 32 KB (current W c-half)
  __shared__ float Xs[TILE_R * CDIM];  // 16 KB
  const int t = threadIdx.x;
  const int m = blockIdx.y;
  const float* tm = (m == 0) ? tmk : (m == 1) ? tmv : tmr;
  const float* Wt = wt + m * 16384;
  float* outb = kvr + (size_t)m * N * CDIM;
  const int n0 = blockIdx.x * TILE_R;

  {  // stage mixed x tile
    const int c4 = (t & 31) * 4;
    const int rb = t >> 5;  // 0..3
    float4 tm4 = *(const float4*)(tm + c4);
#pragma unroll
    for (int k = 0; k < 8; ++k) {
      int r = rb * 8 + k;
      int n = n0 + r;
      if (n < N) {
        float4 xv = *(const float4*)(x + (size_t)n * CDIM + c4);
        float4 pv = *(const float4*)(px + (size_t)n * CDIM + c4);
        float4 xm;
        xm.x = xv.x * tm4.x + pv.x * (1.0f - tm4.x);
        xm.y = xv.y * tm4.y + pv.y * (1.0f - tm4.y);
        xm.z = xv.z * tm4.z + pv.z * (1.0f - tm4.z);
        xm.w = xv.w * tm4.w + pv.w * (1.0f - tm4.w);
        *(float4*)(Xs + r * CDIM + c4) = xm;
      }
    }
  }
  copy_w_half(Ws, Wt, 0, t);
  __syncthreads();

  const int cg = t & 15, rg = t >> 4;
  const int r0 = rg * 4, j0 = cg * 4;
  float4 aA[4], aB[4];
#pragma unroll
  for (int i = 0; i < 4; ++i) {
    aA[i] = make_float4(0.f, 0.f, 0.f, 0.f);
    aB[i] = make_float4(0.f, 0.f, 0.f, 0.f);
  }
  gemm_half(Ws, Xs, 0, r0, j0, aA, aB);
  __syncthreads();
  copy_w_half(Ws, Wt, 1, t);
  __syncthreads();
  gemm_half(Ws, Xs, 64, r0, j0, aA, aB);

#pragma unroll
  for (int i = 0; i < 4; ++i) {
    int n = n0 + r0 + i;
    if (n < N) {
      *(float4*)(outb + (size_t)n * CDIM + j0) = aA[i];
      *(float4*)(outb + (size_t)n * CDIM + 64 + j0) = aB[i];
    }
  }
}

// ---------------- Kernel B: edge stage  out = (r*wkv) @ Wo^T -----------------
__device__ __forceinline__ float edge_elem(float a, float b, float kk, float vv,
                                           float rr, float wd) {
  float ke = expf(fminf(kk, 60.0f));
  float sr = 1.0f / (1.0f + expf(-rr));
  return sr * ((a + wd * ke * vv) / (b + ke + 1e-20f));
}

__global__ __launch_bounds__(BT) void edge_stage(
    const float* __restrict__ ah, const float* __restrict__ bh,
    const int* __restrict__ sidx, const int* __restrict__ tidx,
    const int* __restrict__ ip, const int* __restrict__ Tp,
    const float* __restrict__ time_w, const float* __restrict__ wt,
    const float* __restrict__ kvr, float* __restrict__ out, int N) {
  __shared__ float Ws[64 * CDIM];      // 32 KB
  __shared__ float Ps[TILE_R * CDIM];  // 16 KB
  const int t = threadIdx.x;
  const size_t e0 = (size_t)blockIdx.x * TILE_R;
  const float* WoT = wt + 3 * 16384;
  const float* Kb = kvr;
  const float* Vb = kvr + (size_t)N * CDIM;
  const float* Rb = kvr + 2 * (size_t)N * CDIM;

  {  // elementwise RWKV prologue -> Ps
    const int c4 = (t & 31) * 4;
    const int rb = t >> 5;
    const float dec = -(float)(Tp[0] - ip[0] - 1);
    float4 tw4 = *(const float4*)(time_w + c4);
    float4 wd4;
    wd4.x = expf(dec * tw4.x);
    wd4.y = expf(dec * tw4.y);
    wd4.z = expf(dec * tw4.z);
    wd4.w = expf(dec * tw4.w);
#pragma unroll
    for (int k = 0; k < 8; ++k) {
      int r = rb * 8 + k;
      size_t e = e0 + r;
      int se = sidx[e];
      int te = tidx[e];
      float4 a4 = *(const float4*)(ah + e * CDIM + c4);
      float4 b4 = *(const float4*)(bh + e * CDIM + c4);
      float4 k4 = *(const float4*)(Kb + (size_t)se * CDIM + c4);
      float4 v4 = *(const float4*)(Vb + (size_t)te * CDIM + c4);
      float4 r4 = *(const float4*)(Rb + (size_t)se * CDIM + c4);
      float4 p4;
      p4.x = edge_elem(a4.x, b4.x, k4.x, v4.x, r4.x, wd4.x);
      p4.y = edge_elem(a4.y, b4.y, k4.y, v4.y, r4.y, wd4.y);
      p4.z = edge_elem(a4.z, b4.z, k4.z, v4.z, r4.z, wd4.z);
      p4.w = edge_elem(a4.w, b4.w, k4.w, v4.w, r4.w, wd4.w);
      *(float4*)(Ps + r * CDIM + c4) = p4;
    }
  }
  copy_w_half(Ws, WoT, 0, t);
  __syncthreads();

  const int cg = t & 15, rg = t >> 4;
  const int r0 = rg * 4, j0 = cg * 4;
  float4 aA[4], aB[4];
#pragma unroll
  for (int i = 0; i < 4; ++i) {
    aA[i] = make_float4(0.f, 0.f, 0.f, 0.f);
    aB[i] = make_float4(0.f, 0.f, 0.f, 0.f);
  }
  gemm_half(Ws, Ps, 0, r0, j0, aA, aB);
  __syncthreads();
  copy_w_half(Ws, WoT, 1, t);
  __syncthreads();
  gemm_half(Ws, Ps, 64, r0, j0, aA, aB);

#pragma unroll
  for (int i = 0; i < 4; ++i) {
    size_t e = e0 + r0 + i;
    *(float4*)(out + e * CDIM + j0) = aA[i];
    *(float4*)(out + e * CDIM + 64 + j0) = aB[i];
  }
}

extern "C" void kernel_launch(void* const* d_in, const int* in_sizes, int n_in,
                              void* d_out, int out_size, void* d_ws,
                              size_t ws_size, hipStream_t stream) {
  const float* x   = (const float*)d_in[0];
  const float* px  = (const float*)d_in[1];
  const float* ah  = (const float*)d_in[2];
  const float* bh  = (const float*)d_in[3];
  const float* Wk  = (const float*)d_in[4];
  const float* Wv  = (const float*)d_in[5];
  const float* Wr  = (const float*)d_in[6];
  const float* Wo  = (const float*)d_in[7];
  const float* tmk = (const float*)d_in[8];
  const float* tmv = (const float*)d_in[9];
  const float* tmr = (const float*)d_in[10];
  const float* tw  = (const float*)d_in[11];
  const int* sidx  = (const int*)d_in[12];
  const int* tidx  = (const int*)d_in[13];
  const int* ip    = (const int*)d_in[14];
  const int* Tp    = (const int*)d_in[15];
  const int N = in_sizes[0] / CDIM;   // 25000
  const int E = in_sizes[2] / CDIM;   // 400000

  float* wt  = (float*)d_ws;          // 4 * 16384 floats
  float* kvr = wt + 4 * 16384;        // 3 * N * C floats
  float* out = (float*)d_out;

  transpose_w<<<dim3(64), dim3(256), 0, stream>>>(Wk, Wv, Wr, Wo, wt);
  node_stage<<<dim3((N + TILE_R - 1) / TILE_R, 3), dim3(BT), 0, stream>>>(
      x, px, tmk, tmv, tmr, wt, kvr, N);
  edge_stage<<<dim3(E / TILE_R), dim3(BT), 0, stream>>>(
      ah, bh, sidx, tidx, ip, Tp, tw, wt, kvr, out, N);
}